// Round 8
// baseline (1265.478 us; speedup 1.0000x reference)
//
#include <hip/hip_runtime.h>
#include <math.h>

#define HF 128
#define WPAD 136      // padded LDS row stride (bf16 elems) for MLP tiles
#define BSH 7         // log2(nodes per bucket)
#define NPB 128       // nodes per bucket (= MLP tile)

typedef short bfrag __attribute__((ext_vector_type(8)));   // 8 bf16 (4 VGPRs) - MFMA A/B frag
typedef float facc  __attribute__((ext_vector_type(4)));   // 4 f32 - MFMA C/D frag
typedef float f4v   __attribute__((ext_vector_type(4)));

__device__ __forceinline__ unsigned short f2bf(float x) {
    unsigned int u = __float_as_uint(x);
    unsigned int r = (u + 0x7FFFu + ((u >> 16) & 1u)) >> 16;
    return (unsigned short)r;
}
__device__ __forceinline__ float bflo(unsigned int u) { return __uint_as_float(u << 16); }
__device__ __forceinline__ float bfhi(unsigned int u) { return __uint_as_float(u & 0xffff0000u); }

__device__ __forceinline__ float ssp(float x) {
    const float SHIFT = 0.69314718055994531f;
    return (x > 0.f) ? (x + log1pf(expf(-x)) - SHIFT)
                     : (log1pf(expf(x)) - SHIFT);
}

// ---------------------------------------------------------------------------
// Bucket histogram: 600K atomics over NB counters
// ---------------------------------------------------------------------------
__global__ void bhist_kernel(const int* __restrict__ tgt, int* __restrict__ bc, int E) {
    int eid = blockIdx.x * blockDim.x + threadIdx.x;
    if (eid < E) atomicAdd(&bc[tgt[eid] >> BSH], 1);
}

// single-block exclusive scan over NB (<=512) bucket counts; writes offsets + cursor
__global__ __launch_bounds__(512) void bscan_kernel(const int* __restrict__ bc,
                                                    int* __restrict__ boff,
                                                    int* __restrict__ bcur,
                                                    int NB, int E) {
    __shared__ int ws[8];
    int t = threadIdx.x, lane = t & 63, wv = t >> 6;
    int val = (t < NB) ? bc[t] : 0;
    int x = val;
    #pragma unroll
    for (int d = 1; d < 64; d <<= 1) {
        int y = __shfl_up(x, d, 64);
        if (lane >= d) x += y;
    }
    if (lane == 63) ws[wv] = x;
    __syncthreads();
    if (wv == 0 && lane < 8) {
        int s = ws[lane];
        #pragma unroll
        for (int d = 1; d < 8; d <<= 1) {
            int y = __shfl_up(s, d, 64);
            if (lane >= d) s += y;
        }
        ws[lane] = s;
    }
    __syncthreads();
    int pre = ((wv > 0) ? ws[wv - 1] : 0) + (x - val);
    if (t < NB) { boff[t] = pre; bcur[t] = pre; }
    if (t == 0) boff[NB] = E;
}

// ---------------------------------------------------------------------------
// Partition: stream e sequentially (nt), convert rows to bf16, write each
// 256 B row to its bucket's next slot (NB advancing write streams) + aux id.
// One wave handles 4 consecutive edges per iteration.
// ---------------------------------------------------------------------------
__global__ __launch_bounds__(256) void partition_kernel(
        const float* __restrict__ e, const int* __restrict__ tgt,
        int* __restrict__ bcur, unsigned int* __restrict__ bdata,
        int* __restrict__ aux, int E) {
    int nw = (gridDim.x * blockDim.x) >> 6;
    int gw = (blockIdx.x * blockDim.x + threadIdx.x) >> 6;
    int lane = threadIdx.x & 63;
    for (long long base = (long long)gw * 4; base < E; base += (long long)nw * 4) {
        int cnt = (int)min((long long)4, (long long)E - base);
        // independent row loads issued first (lane l holds feats l and l+64)
        float lo[4], hi[4];
        #pragma unroll
        for (int j = 0; j < 4; ++j) {
            long long eid = base + ((j < cnt) ? j : 0);
            lo[j] = __builtin_nontemporal_load(e + eid * HF + lane);
            hi[j] = __builtin_nontemporal_load(e + eid * HF + 64 + lane);
        }
        int t_ = 0, slot_ = 0;
        if (lane < cnt) {
            t_ = tgt[base + lane];
            slot_ = atomicAdd(&bcur[t_ >> BSH], 1);
            aux[slot_] = t_;
        }
        #pragma unroll
        for (int j = 0; j < 4; ++j) {
            if (j < cnt) {
                int sj = __shfl(slot_, j, 64);
                unsigned int o = ((unsigned int)f2bf(hi[j]) << 16) | f2bf(lo[j]);
                bdata[(size_t)sj * 64 + lane] = o;
            }
        }
    }
}

// ---------------------------------------------------------------------------
// Reduce: one block per bucket. 64 KB LDS f32 accumulator [128 nodes][128 f].
// Sequential reads of the bucket's records; LDS atomic f32 accumulate
// (lane l -> feats l, l+64: 2-way banks, free). Writes bf16 agg rows.
// ---------------------------------------------------------------------------
__global__ __launch_bounds__(512) void reduce_kernel(
        const unsigned int* __restrict__ bdata, const int* __restrict__ aux,
        const int* __restrict__ boff, unsigned short* __restrict__ aggb, int N) {
    __shared__ float acc[NPB * HF];   // 64 KB
    int tid = threadIdx.x, lane = tid & 63, wv = tid >> 6;
    #pragma unroll
    for (int i = tid; i < NPB * HF / 4; i += 512)
        ((f4v*)acc)[i] = (f4v){0.f, 0.f, 0.f, 0.f};
    __syncthreads();

    int b = blockIdx.x;
    int beg = boff[b], end = boff[b + 1];
    int per = (end - beg + 7) >> 3;
    int wbeg = beg + wv * per;
    int wend = min(wbeg + per, end);
    int r = wbeg;
    for (; r + 4 <= wend; r += 4) {
        int a0 = aux[r + 0] & (NPB - 1);
        int a1 = aux[r + 1] & (NPB - 1);
        int a2 = aux[r + 2] & (NPB - 1);
        int a3 = aux[r + 3] & (NPB - 1);
        unsigned int d0 = bdata[(size_t)(r + 0) * 64 + lane];
        unsigned int d1 = bdata[(size_t)(r + 1) * 64 + lane];
        unsigned int d2 = bdata[(size_t)(r + 2) * 64 + lane];
        unsigned int d3 = bdata[(size_t)(r + 3) * 64 + lane];
        atomicAdd(&acc[a0 * HF + lane],      bflo(d0));
        atomicAdd(&acc[a0 * HF + 64 + lane], bfhi(d0));
        atomicAdd(&acc[a1 * HF + lane],      bflo(d1));
        atomicAdd(&acc[a1 * HF + 64 + lane], bfhi(d1));
        atomicAdd(&acc[a2 * HF + lane],      bflo(d2));
        atomicAdd(&acc[a2 * HF + 64 + lane], bfhi(d2));
        atomicAdd(&acc[a3 * HF + lane],      bflo(d3));
        atomicAdd(&acc[a3 * HF + 64 + lane], bfhi(d3));
    }
    for (; r < wend; ++r) {
        int a0 = aux[r] & (NPB - 1);
        unsigned int d0 = bdata[(size_t)r * 64 + lane];
        atomicAdd(&acc[a0 * HF + lane],      bflo(d0));
        atomicAdd(&acc[a0 * HF + 64 + lane], bfhi(d0));
    }
    __syncthreads();

    int nbase = b << BSH;
    for (int idx = tid; idx < NPB * 64; idx += 512) {
        int row = idx >> 6, c = idx & 63;
        int node = nbase + row;
        if (node < N) {
            unsigned int o = ((unsigned int)f2bf(acc[row * HF + 2 * c + 1]) << 16)
                           | f2bf(acc[row * HF + 2 * c]);
            ((unsigned int*)aggb)[(size_t)node * 64 + c] = o;
        }
    }
}

// ---------------------------------------------------------------------------
// MFMA MLP: out = v + ( ssp(agg @ w1 + b1) @ w2 + b2 )   (unchanged from R5)
// ---------------------------------------------------------------------------
__global__ __launch_bounds__(512) void mlp_mfma_kernel(
        const unsigned short* __restrict__ aggb,
        const float* __restrict__ v,
        const float* __restrict__ w1, const float* __restrict__ b1,
        const float* __restrict__ w2, const float* __restrict__ b2,
        float* __restrict__ out, int N, int ngroups) {
    __shared__ unsigned short wt1[HF * WPAD];
    __shared__ unsigned short wt2[HF * WPAD];
    __shared__ unsigned short atile[HF * WPAD];

    int tid = threadIdx.x;
    for (int idx = tid; idx < HF * HF; idx += 512) {
        int k = idx >> 7, n = idx & 127;
        wt1[n * WPAD + k] = f2bf(w1[idx]);
        wt2[n * WPAD + k] = f2bf(w2[idx]);
    }

    int w = tid >> 6, lane = tid & 63;
    int wr = (w & 3) * 32;
    int wchalf = (w >> 2) * 64;
    int lr = lane & 15;
    int kg = lane >> 4;
    float bias1[4], bias2[4];
    #pragma unroll
    for (int nt = 0; nt < 4; ++nt) {
        int col = wchalf + nt * 16 + lr;
        bias1[nt] = b1[col];
        bias2[nt] = b2[col];
    }

    for (int g = blockIdx.x; g < ngroups; g += gridDim.x) {
        int base = g * HF;
        __syncthreads();

        for (int idx = tid; idx < HF * 16; idx += 512) {
            int r = idx >> 4, c = idx & 15;
            int row = base + r;
            bfrag val = {0,0,0,0,0,0,0,0};
            if (row < N) val = *(const bfrag*)(aggb + (size_t)row * HF + c * 8);
            *(bfrag*)(atile + r * WPAD + c * 8) = val;
        }
        __syncthreads();

        facc acc[2][4];
        #pragma unroll
        for (int m = 0; m < 2; ++m)
            #pragma unroll
            for (int nt = 0; nt < 4; ++nt)
                acc[m][nt] = (facc){0.f, 0.f, 0.f, 0.f};
        #pragma unroll
        for (int ks = 0; ks < 4; ++ks) {
            int k0 = ks * 32 + kg * 8;
            bfrag a0 = *(const bfrag*)(atile + (wr + lr) * WPAD + k0);
            bfrag a1 = *(const bfrag*)(atile + (wr + 16 + lr) * WPAD + k0);
            #pragma unroll
            for (int nt = 0; nt < 4; ++nt) {
                bfrag b = *(const bfrag*)(wt1 + (wchalf + nt * 16 + lr) * WPAD + k0);
                acc[0][nt] = __builtin_amdgcn_mfma_f32_16x16x32_bf16(a0, b, acc[0][nt], 0, 0, 0);
                acc[1][nt] = __builtin_amdgcn_mfma_f32_16x16x32_bf16(a1, b, acc[1][nt], 0, 0, 0);
            }
        }
        __syncthreads();

        #pragma unroll
        for (int m = 0; m < 2; ++m) {
            int rbase = wr + m * 16 + kg * 4;
            #pragma unroll
            for (int nt = 0; nt < 4; ++nt) {
                int col = wchalf + nt * 16 + lr;
                #pragma unroll
                for (int i = 0; i < 4; ++i) {
                    float h = ssp(acc[m][nt][i] + bias1[nt]);
                    atile[(rbase + i) * WPAD + col] = f2bf(h);
                }
            }
        }
        __syncthreads();

        facc acc2[2][4];
        #pragma unroll
        for (int m = 0; m < 2; ++m)
            #pragma unroll
            for (int nt = 0; nt < 4; ++nt)
                acc2[m][nt] = (facc){0.f, 0.f, 0.f, 0.f};
        #pragma unroll
        for (int ks = 0; ks < 4; ++ks) {
            int k0 = ks * 32 + kg * 8;
            bfrag a0 = *(const bfrag*)(atile + (wr + lr) * WPAD + k0);
            bfrag a1 = *(const bfrag*)(atile + (wr + 16 + lr) * WPAD + k0);
            #pragma unroll
            for (int nt = 0; nt < 4; ++nt) {
                bfrag b = *(const bfrag*)(wt2 + (wchalf + nt * 16 + lr) * WPAD + k0);
                acc2[0][nt] = __builtin_amdgcn_mfma_f32_16x16x32_bf16(a0, b, acc2[0][nt], 0, 0, 0);
                acc2[1][nt] = __builtin_amdgcn_mfma_f32_16x16x32_bf16(a1, b, acc2[1][nt], 0, 0, 0);
            }
        }

        #pragma unroll
        for (int m = 0; m < 2; ++m) {
            #pragma unroll
            for (int i = 0; i < 4; ++i) {
                int row = base + wr + m * 16 + kg * 4 + i;
                if (row < N) {
                    #pragma unroll
                    for (int nt = 0; nt < 4; ++nt) {
                        int col = wchalf + nt * 16 + lr;
                        out[(size_t)row * HF + col] = acc2[m][nt][i] + bias2[nt] + v[(size_t)row * HF + col];
                    }
                }
            }
        }
    }
}

// ---------------------------------------------------------------------------
// Fallback path (ws too small / NB too large): atomic scatter + f32 MLP
// ---------------------------------------------------------------------------
__global__ void scatter_add_kernel(const float* __restrict__ e,
                                   const int* __restrict__ tgt,
                                   float* __restrict__ agg, int E) {
    int t = blockIdx.x * blockDim.x + threadIdx.x;
    int eid = t >> 5;
    if (eid >= E) return;
    int c = t & 31;
    int dst = tgt[eid];
    float4 val = *reinterpret_cast<const float4*>(e + (size_t)eid * HF + c * 4);
    float* p = agg + (size_t)dst * HF + c * 4;
    unsafeAtomicAdd(p + 0, val.x);
    unsafeAtomicAdd(p + 1, val.y);
    unsafeAtomicAdd(p + 2, val.z);
    unsafeAtomicAdd(p + 3, val.w);
}

__device__ __forceinline__ void fma4(float4& acc, float a, const float4& w) {
    acc.x = fmaf(a, w.x, acc.x);
    acc.y = fmaf(a, w.y, acc.y);
    acc.z = fmaf(a, w.z, acc.z);
    acc.w = fmaf(a, w.w, acc.w);
}

__global__ __launch_bounds__(512) void mlp_kernel(
        float* __restrict__ data, const float* __restrict__ v,
        const float* __restrict__ w1, const float* __restrict__ b1,
        const float* __restrict__ w2, const float* __restrict__ b2, int N) {
    __shared__ float w1s[HF * HF];
    __shared__ float w2s[HF * HF];
    __shared__ float tile[32][HF];
    int tid = threadIdx.x;
    float4* w1sv = (float4*)w1s; float4* w2sv = (float4*)w2s;
    for (int i = tid; i < HF * HF / 4; i += 512) {
        w1sv[i] = ((const float4*)w1)[i];
        w2sv[i] = ((const float4*)w2)[i];
    }
    int nl = tid >> 5, fblk = tid & 31;
    float4 bb1 = ((const float4*)b1)[fblk];
    float4 bb2 = ((const float4*)b2)[fblk];
    float4* tilev = (float4*)tile;
    int ngroups = (N + 31) / 32;
    for (int g = blockIdx.x; g < ngroups; g += gridDim.x) {
        int base = g * 32;
        __syncthreads();
        for (int i = tid; i < 32 * (HF / 4); i += 512) {
            int node = base + (i >> 5);
            float4 val = make_float4(0.f, 0.f, 0.f, 0.f);
            if (node < N) val = ((const float4*)data)[(size_t)node * (HF / 4) + (i & 31)];
            tilev[i] = val;
        }
        __syncthreads();
        float4 a0 = bb1, a1 = bb1;
        #pragma unroll 8
        for (int k = 0; k < HF; ++k) {
            float x0 = tile[nl][k], x1 = tile[nl + 16][k];
            float4 w = w1sv[k * 32 + fblk];
            fma4(a0, x0, w); fma4(a1, x1, w);
        }
        a0.x = ssp(a0.x); a0.y = ssp(a0.y); a0.z = ssp(a0.z); a0.w = ssp(a0.w);
        a1.x = ssp(a1.x); a1.y = ssp(a1.y); a1.z = ssp(a1.z); a1.w = ssp(a1.w);
        __syncthreads();
        tilev[nl * 32 + fblk] = a0;
        tilev[(nl + 16) * 32 + fblk] = a1;
        __syncthreads();
        float4 c0 = bb2, c1 = bb2;
        #pragma unroll 8
        for (int k = 0; k < HF; ++k) {
            float x0 = tile[nl][k], x1 = tile[nl + 16][k];
            float4 w = w2sv[k * 32 + fblk];
            fma4(c0, x0, w); fma4(c1, x1, w);
        }
        int n0 = base + nl, n1 = base + nl + 16;
        if (n0 < N) {
            float4 vv = ((const float4*)v)[(size_t)n0 * 32 + fblk];
            c0.x += vv.x; c0.y += vv.y; c0.z += vv.z; c0.w += vv.w;
            ((float4*)data)[(size_t)n0 * 32 + fblk] = c0;
        }
        if (n1 < N) {
            float4 vv = ((const float4*)v)[(size_t)n1 * 32 + fblk];
            c1.x += vv.x; c1.y += vv.y; c1.z += vv.z; c1.w += vv.w;
            ((float4*)data)[(size_t)n1 * 32 + fblk] = c1;
        }
    }
}

extern "C" void kernel_launch(void* const* d_in, const int* in_sizes, int n_in,
                              void* d_out, int out_size, void* d_ws, size_t ws_size,
                              hipStream_t stream) {
    const float* v  = (const float*)d_in[0];
    const float* e  = (const float*)d_in[1];
    const int*   ei = (const int*)d_in[2];
    const float* w1 = (const float*)d_in[3];
    const float* b1 = (const float*)d_in[4];
    const float* w2 = (const float*)d_in[5];
    const float* b2 = (const float*)d_in[6];
    float* out = (float*)d_out;

    int N = in_sizes[0] / HF;    // 50000
    int E = in_sizes[2] / 2;     // 600000
    const int* tgt = ei + E;     // edge_index[1]

    int NB = (N + NPB - 1) >> BSH;   // 391

    // ws: bc[NB] | boff[NB+1] | bcur[NB] | aux[E] | pad | bdata[E*64 u32] | aggb[N*HF bf16]
    size_t ints = (size_t)NB * 3 + 1 + E;
    size_t needed = ints * 4 + 32 + (size_t)E * HF * 2 + (size_t)N * HF * 2;
    if (ws_size >= needed && NB <= 512) {
        int* bc   = (int*)d_ws;
        int* boff = bc + NB;
        int* bcur = boff + NB + 1;
        int* aux  = bcur + NB;
        uintptr_t p = (uintptr_t)(aux + E);
        p = (p + 15) & ~(uintptr_t)15;
        unsigned int* bdata = (unsigned int*)p;
        unsigned short* aggb = (unsigned short*)(bdata + (size_t)E * 64);

        hipMemsetAsync(bc, 0, (size_t)NB * sizeof(int), stream);
        bhist_kernel<<<(E + 255) / 256, 256, 0, stream>>>(tgt, bc, E);
        bscan_kernel<<<1, 512, 0, stream>>>(bc, boff, bcur, NB, E);
        partition_kernel<<<2048, 256, 0, stream>>>(e, tgt, bcur, bdata, aux, E);
        reduce_kernel<<<NB, 512, 0, stream>>>(bdata, aux, boff, aggb, N);

        int ngroups = (N + HF - 1) / HF;  // 391
        mlp_mfma_kernel<<<256, 512, 0, stream>>>(aggb, v, w1, b1, w2, b2, out, N, ngroups);
    } else {
        hipMemsetAsync(out, 0, (size_t)N * HF * sizeof(float), stream);
        long long total_t = (long long)E * 32;
        scatter_add_kernel<<<(int)((total_t + 255) / 256), 256, 0, stream>>>(e, tgt, out, E);
        mlp_kernel<<<512, 512, 0, stream>>>(out, v, w1, b1, w2, b2, N);
    }
}

// Round 9
// 241.427 us; speedup vs baseline: 5.2417x; 5.2417x over previous
//
#include <hip/hip_runtime.h>
#include <math.h>

#define HF 128
#define WPAD 136      // padded LDS row stride (bf16 elems) for MLP tiles

typedef short bfrag __attribute__((ext_vector_type(8)));   // 8 bf16 (4 VGPRs) - MFMA A/B frag
typedef float facc  __attribute__((ext_vector_type(4)));   // 4 f32 - MFMA C/D frag
typedef float f4v   __attribute__((ext_vector_type(4)));

__device__ __forceinline__ unsigned short f2bf(float x) {
    unsigned int u = __float_as_uint(x);
    unsigned int r = (u + 0x7FFFu + ((u >> 16) & 1u)) >> 16;
    return (unsigned short)r;
}
__device__ __forceinline__ float bflo(unsigned int u) { return __uint_as_float(u << 16); }
__device__ __forceinline__ float bfhi(unsigned int u) { return __uint_as_float(u & 0xffff0000u); }

__device__ __forceinline__ float ssp(float x) {
    const float SHIFT = 0.69314718055994531f;
    return (x > 0.f) ? (x + log1pf(expf(-x)) - SHIFT)
                     : (log1pf(expf(x)) - SHIFT);
}

// ---------------------------------------------------------------------------
// Fused: (a) stream-convert e (f32, nt loads, sequential) -> eb (bf16x2 u32,
// sequential regular stores => L3-resident, 153 MB < 256 MB L3);
// (b) histogram of targets into counts.
// ---------------------------------------------------------------------------
__global__ __launch_bounds__(256) void conv_hist_kernel(
        const float* __restrict__ e, const int* __restrict__ tgt,
        int* __restrict__ counts, unsigned int* __restrict__ eb,
        long long nq, int E) {
    long long stride = (long long)gridDim.x * blockDim.x;
    long long tid = (long long)blockIdx.x * blockDim.x + threadIdx.x;
    for (long long i = tid; i < nq; i += stride) {
        f4v r = __builtin_nontemporal_load(((const f4v*)e) + i);
        uint2 o;
        o.x = ((unsigned int)f2bf(r.y) << 16) | f2bf(r.x);
        o.y = ((unsigned int)f2bf(r.w) << 16) | f2bf(r.z);
        ((uint2*)eb)[i] = o;   // regular store: we WANT this resident in L3
    }
    for (long long i = tid; i < E; i += stride)
        atomicAdd(&counts[tgt[i]], 1);
}

// ---------------------------------------------------------------------------
// CSR scan (block-local then fused cross-block fixup)
// ---------------------------------------------------------------------------
__global__ __launch_bounds__(1024) void scan1_kernel(const int* __restrict__ counts,
                                                     int* __restrict__ offsets,
                                                     int* __restrict__ bsum, int N) {
    __shared__ int ws[16];
    int t = threadIdx.x;
    int i = blockIdx.x * 1024 + t;
    int lane = t & 63, wv = t >> 6;
    int val = (i < N) ? counts[i] : 0;
    int x = val;
    #pragma unroll
    for (int d = 1; d < 64; d <<= 1) {
        int y = __shfl_up(x, d, 64);
        if (lane >= d) x += y;
    }
    if (lane == 63) ws[wv] = x;
    __syncthreads();
    if (wv == 0) {
        int s = (lane < 16) ? ws[lane] : 0;
        #pragma unroll
        for (int d = 1; d < 16; d <<= 1) {
            int y = __shfl_up(s, d, 64);
            if (lane >= d) s += y;
        }
        if (lane < 16) ws[lane] = s;
    }
    __syncthreads();
    int pre = ((wv > 0) ? ws[wv - 1] : 0) + (x - val);
    if (i < N) offsets[i] = pre;
    if (t == 0) bsum[blockIdx.x] = ws[15];
}

__global__ __launch_bounds__(1024) void scan23_kernel(int* __restrict__ offsets,
                                                      const int* __restrict__ bsum,
                                                      int N, int E, int nb) {
    __shared__ int pre_s;
    int t = threadIdx.x;
    if (t < 64) {
        int v = (t < nb && t < (int)blockIdx.x) ? bsum[t] : 0;
        #pragma unroll
        for (int d = 32; d > 0; d >>= 1) v += __shfl_down(v, d, 64);
        if (t == 0) pre_s = v;
    }
    __syncthreads();
    int i = blockIdx.x * 1024 + t;
    if (i < N) offsets[i] += pre_s;
    if (blockIdx.x == 0 && t == 0) offsets[N] = E;
}

// counts doubles as cursor: atomicSub yields a unique slot in [0, count)
__global__ void fill_kernel(const int* __restrict__ tgt, const int* __restrict__ offsets,
                            int* __restrict__ counts, int* __restrict__ edge_list, int E) {
    int eid = blockIdx.x * blockDim.x + threadIdx.x;
    if (eid >= E) return;
    int t = tgt[eid];
    int pos = atomicSub(&counts[t], 1) - 1;
    edge_list[offsets[t] + pos] = eid;
}

// ---------------------------------------------------------------------------
// Gather from L3-resident bf16 eb: one wave per node; row = 256 B = 64 lanes
// x u32 (2 feats each). 8 rows in flight (regular loads -> L3 hits).
// ---------------------------------------------------------------------------
__global__ __launch_bounds__(256) void gather_eb_kernel(
        const unsigned int* __restrict__ eb, const int* __restrict__ edge_list,
        const int* __restrict__ offsets, unsigned int* __restrict__ aggb32, int N) {
    int node = (blockIdx.x * blockDim.x + threadIdx.x) >> 6;
    if (node >= N) return;
    int lane = threadIdx.x & 63;
    int beg = offsets[node], end = offsets[node + 1];
    float s0 = 0.f, s1 = 0.f, t0 = 0.f, t1 = 0.f;
    float u0 = 0.f, u1 = 0.f, p0 = 0.f, p1 = 0.f;
    int j = beg;
    for (; j + 8 <= end; j += 8) {
        int e0 = edge_list[j + 0], e1 = edge_list[j + 1];
        int e2 = edge_list[j + 2], e3 = edge_list[j + 3];
        int e4 = edge_list[j + 4], e5 = edge_list[j + 5];
        int e6 = edge_list[j + 6], e7 = edge_list[j + 7];
        unsigned int a0 = eb[(size_t)e0 * 64 + lane];
        unsigned int a1 = eb[(size_t)e1 * 64 + lane];
        unsigned int a2 = eb[(size_t)e2 * 64 + lane];
        unsigned int a3 = eb[(size_t)e3 * 64 + lane];
        unsigned int a4 = eb[(size_t)e4 * 64 + lane];
        unsigned int a5 = eb[(size_t)e5 * 64 + lane];
        unsigned int a6 = eb[(size_t)e6 * 64 + lane];
        unsigned int a7 = eb[(size_t)e7 * 64 + lane];
        s0 += bflo(a0); s1 += bfhi(a0);
        t0 += bflo(a1); t1 += bfhi(a1);
        u0 += bflo(a2); u1 += bfhi(a2);
        p0 += bflo(a3); p1 += bfhi(a3);
        s0 += bflo(a4); s1 += bfhi(a4);
        t0 += bflo(a5); t1 += bfhi(a5);
        u0 += bflo(a6); u1 += bfhi(a6);
        p0 += bflo(a7); p1 += bfhi(a7);
    }
    if (j + 4 <= end) {
        unsigned int a0 = eb[(size_t)edge_list[j + 0] * 64 + lane];
        unsigned int a1 = eb[(size_t)edge_list[j + 1] * 64 + lane];
        unsigned int a2 = eb[(size_t)edge_list[j + 2] * 64 + lane];
        unsigned int a3 = eb[(size_t)edge_list[j + 3] * 64 + lane];
        s0 += bflo(a0); s1 += bfhi(a0);
        t0 += bflo(a1); t1 += bfhi(a1);
        u0 += bflo(a2); u1 += bfhi(a2);
        p0 += bflo(a3); p1 += bfhi(a3);
        j += 4;
    }
    if (j + 2 <= end) {
        unsigned int a0 = eb[(size_t)edge_list[j + 0] * 64 + lane];
        unsigned int a1 = eb[(size_t)edge_list[j + 1] * 64 + lane];
        s0 += bflo(a0); s1 += bfhi(a0);
        t0 += bflo(a1); t1 += bfhi(a1);
        j += 2;
    }
    if (j < end) {
        unsigned int a0 = eb[(size_t)edge_list[j] * 64 + lane];
        s0 += bflo(a0); s1 += bfhi(a0);
    }
    s0 += t0 + u0 + p0;
    s1 += t1 + u1 + p1;
    unsigned int o = ((unsigned int)f2bf(s1) << 16) | f2bf(s0);
    aggb32[(size_t)node * 64 + lane] = o;
}

// ---------------------------------------------------------------------------
// MFMA MLP: out = v + ( ssp(agg @ w1 + b1) @ w2 + b2 )   (unchanged, known-good)
// 512 thr (8 waves), 128-node tiles. wave w: rows (w&3)*32, cols (w>>2)*64.
// C/D: col=lane&15, row=4*(lane>>4)+i  [guide m89].
// ---------------------------------------------------------------------------
__global__ __launch_bounds__(512) void mlp_mfma_kernel(
        const unsigned short* __restrict__ aggb,
        const float* __restrict__ v,
        const float* __restrict__ w1, const float* __restrict__ b1,
        const float* __restrict__ w2, const float* __restrict__ b2,
        float* __restrict__ out, int N, int ngroups) {
    __shared__ unsigned short wt1[HF * WPAD];
    __shared__ unsigned short wt2[HF * WPAD];
    __shared__ unsigned short atile[HF * WPAD];

    int tid = threadIdx.x;
    for (int idx = tid; idx < HF * HF; idx += 512) {
        int k = idx >> 7, n = idx & 127;
        wt1[n * WPAD + k] = f2bf(w1[idx]);
        wt2[n * WPAD + k] = f2bf(w2[idx]);
    }

    int w = tid >> 6, lane = tid & 63;
    int wr = (w & 3) * 32;
    int wchalf = (w >> 2) * 64;
    int lr = lane & 15;
    int kg = lane >> 4;
    float bias1[4], bias2[4];
    #pragma unroll
    for (int nt = 0; nt < 4; ++nt) {
        int col = wchalf + nt * 16 + lr;
        bias1[nt] = b1[col];
        bias2[nt] = b2[col];
    }

    for (int g = blockIdx.x; g < ngroups; g += gridDim.x) {
        int base = g * HF;
        __syncthreads();

        for (int idx = tid; idx < HF * 16; idx += 512) {
            int r = idx >> 4, c = idx & 15;
            int row = base + r;
            bfrag val = {0,0,0,0,0,0,0,0};
            if (row < N) val = *(const bfrag*)(aggb + (size_t)row * HF + c * 8);
            *(bfrag*)(atile + r * WPAD + c * 8) = val;
        }
        __syncthreads();

        facc acc[2][4];
        #pragma unroll
        for (int m = 0; m < 2; ++m)
            #pragma unroll
            for (int nt = 0; nt < 4; ++nt)
                acc[m][nt] = (facc){0.f, 0.f, 0.f, 0.f};
        #pragma unroll
        for (int ks = 0; ks < 4; ++ks) {
            int k0 = ks * 32 + kg * 8;
            bfrag a0 = *(const bfrag*)(atile + (wr + lr) * WPAD + k0);
            bfrag a1 = *(const bfrag*)(atile + (wr + 16 + lr) * WPAD + k0);
            #pragma unroll
            for (int nt = 0; nt < 4; ++nt) {
                bfrag b = *(const bfrag*)(wt1 + (wchalf + nt * 16 + lr) * WPAD + k0);
                acc[0][nt] = __builtin_amdgcn_mfma_f32_16x16x32_bf16(a0, b, acc[0][nt], 0, 0, 0);
                acc[1][nt] = __builtin_amdgcn_mfma_f32_16x16x32_bf16(a1, b, acc[1][nt], 0, 0, 0);
            }
        }
        __syncthreads();

        #pragma unroll
        for (int m = 0; m < 2; ++m) {
            int rbase = wr + m * 16 + kg * 4;
            #pragma unroll
            for (int nt = 0; nt < 4; ++nt) {
                int col = wchalf + nt * 16 + lr;
                #pragma unroll
                for (int i = 0; i < 4; ++i) {
                    float h = ssp(acc[m][nt][i] + bias1[nt]);
                    atile[(rbase + i) * WPAD + col] = f2bf(h);
                }
            }
        }
        __syncthreads();

        facc acc2[2][4];
        #pragma unroll
        for (int m = 0; m < 2; ++m)
            #pragma unroll
            for (int nt = 0; nt < 4; ++nt)
                acc2[m][nt] = (facc){0.f, 0.f, 0.f, 0.f};
        #pragma unroll
        for (int ks = 0; ks < 4; ++ks) {
            int k0 = ks * 32 + kg * 8;
            bfrag a0 = *(const bfrag*)(atile + (wr + lr) * WPAD + k0);
            bfrag a1 = *(const bfrag*)(atile + (wr + 16 + lr) * WPAD + k0);
            #pragma unroll
            for (int nt = 0; nt < 4; ++nt) {
                bfrag b = *(const bfrag*)(wt2 + (wchalf + nt * 16 + lr) * WPAD + k0);
                acc2[0][nt] = __builtin_amdgcn_mfma_f32_16x16x32_bf16(a0, b, acc2[0][nt], 0, 0, 0);
                acc2[1][nt] = __builtin_amdgcn_mfma_f32_16x16x32_bf16(a1, b, acc2[1][nt], 0, 0, 0);
            }
        }

        #pragma unroll
        for (int m = 0; m < 2; ++m) {
            #pragma unroll
            for (int i = 0; i < 4; ++i) {
                int row = base + wr + m * 16 + kg * 4 + i;
                if (row < N) {
                    #pragma unroll
                    for (int nt = 0; nt < 4; ++nt) {
                        int col = wchalf + nt * 16 + lr;
                        out[(size_t)row * HF + col] = acc2[m][nt][i] + bias2[nt] + v[(size_t)row * HF + col];
                    }
                }
            }
        }
    }
}

// ---------------------------------------------------------------------------
// Fallback path (ws too small): atomic scatter + f32 vector MLP
// ---------------------------------------------------------------------------
__global__ void scatter_add_kernel(const float* __restrict__ e,
                                   const int* __restrict__ tgt,
                                   float* __restrict__ agg, int E) {
    int t = blockIdx.x * blockDim.x + threadIdx.x;
    int eid = t >> 5;
    if (eid >= E) return;
    int c = t & 31;
    int dst = tgt[eid];
    float4 val = *reinterpret_cast<const float4*>(e + (size_t)eid * HF + c * 4);
    float* p = agg + (size_t)dst * HF + c * 4;
    unsafeAtomicAdd(p + 0, val.x);
    unsafeAtomicAdd(p + 1, val.y);
    unsafeAtomicAdd(p + 2, val.z);
    unsafeAtomicAdd(p + 3, val.w);
}

__device__ __forceinline__ void fma4(float4& acc, float a, const float4& w) {
    acc.x = fmaf(a, w.x, acc.x);
    acc.y = fmaf(a, w.y, acc.y);
    acc.z = fmaf(a, w.z, acc.z);
    acc.w = fmaf(a, w.w, acc.w);
}

__global__ __launch_bounds__(512) void mlp_kernel(
        float* __restrict__ data, const float* __restrict__ v,
        const float* __restrict__ w1, const float* __restrict__ b1,
        const float* __restrict__ w2, const float* __restrict__ b2, int N) {
    __shared__ float w1s[HF * HF];
    __shared__ float w2s[HF * HF];
    __shared__ float tile[32][HF];
    int tid = threadIdx.x;
    float4* w1sv = (float4*)w1s; float4* w2sv = (float4*)w2s;
    for (int i = tid; i < HF * HF / 4; i += 512) {
        w1sv[i] = ((const float4*)w1)[i];
        w2sv[i] = ((const float4*)w2)[i];
    }
    int nl = tid >> 5, fblk = tid & 31;
    float4 bb1 = ((const float4*)b1)[fblk];
    float4 bb2 = ((const float4*)b2)[fblk];
    float4* tilev = (float4*)tile;
    int ngroups = (N + 31) / 32;
    for (int g = blockIdx.x; g < ngroups; g += gridDim.x) {
        int base = g * 32;
        __syncthreads();
        for (int i = tid; i < 32 * (HF / 4); i += 512) {
            int node = base + (i >> 5);
            float4 val = make_float4(0.f, 0.f, 0.f, 0.f);
            if (node < N) val = ((const float4*)data)[(size_t)node * (HF / 4) + (i & 31)];
            tilev[i] = val;
        }
        __syncthreads();
        float4 a0 = bb1, a1 = bb1;
        #pragma unroll 8
        for (int k = 0; k < HF; ++k) {
            float x0 = tile[nl][k], x1 = tile[nl + 16][k];
            float4 w = w1sv[k * 32 + fblk];
            fma4(a0, x0, w); fma4(a1, x1, w);
        }
        a0.x = ssp(a0.x); a0.y = ssp(a0.y); a0.z = ssp(a0.z); a0.w = ssp(a0.w);
        a1.x = ssp(a1.x); a1.y = ssp(a1.y); a1.z = ssp(a1.z); a1.w = ssp(a1.w);
        __syncthreads();
        tilev[nl * 32 + fblk] = a0;
        tilev[(nl + 16) * 32 + fblk] = a1;
        __syncthreads();
        float4 c0 = bb2, c1 = bb2;
        #pragma unroll 8
        for (int k = 0; k < HF; ++k) {
            float x0 = tile[nl][k], x1 = tile[nl + 16][k];
            float4 w = w2sv[k * 32 + fblk];
            fma4(c0, x0, w); fma4(c1, x1, w);
        }
        int n0 = base + nl, n1 = base + nl + 16;
        if (n0 < N) {
            float4 vv = ((const float4*)v)[(size_t)n0 * 32 + fblk];
            c0.x += vv.x; c0.y += vv.y; c0.z += vv.z; c0.w += vv.w;
            ((float4*)data)[(size_t)n0 * 32 + fblk] = c0;
        }
        if (n1 < N) {
            float4 vv = ((const float4*)v)[(size_t)n1 * 32 + fblk];
            c1.x += vv.x; c1.y += vv.y; c1.z += vv.z; c1.w += vv.w;
            ((float4*)data)[(size_t)n1 * 32 + fblk] = c1;
        }
    }
}

extern "C" void kernel_launch(void* const* d_in, const int* in_sizes, int n_in,
                              void* d_out, int out_size, void* d_ws, size_t ws_size,
                              hipStream_t stream) {
    const float* v  = (const float*)d_in[0];
    const float* e  = (const float*)d_in[1];
    const int*   ei = (const int*)d_in[2];
    const float* w1 = (const float*)d_in[3];
    const float* b1 = (const float*)d_in[4];
    const float* w2 = (const float*)d_in[5];
    const float* b2 = (const float*)d_in[6];
    float* out = (float*)d_out;

    int N = in_sizes[0] / HF;    // 50000
    int E = in_sizes[2] / 2;     // 600000
    const int* tgt = ei + E;     // edge_index[1]

    // ws: counts[N] | offsets[N+1] | bsum[64] | edge_list[E] | pad | eb[E*64 u32] | aggb[N*64 u32]
    size_t ints = (size_t)N + (N + 1) + 64 + E;
    size_t needed = ints * 4 + 32 + (size_t)E * HF * 2 + (size_t)N * HF * 2;
    if (ws_size >= needed) {
        int* counts    = (int*)d_ws;
        int* offsets   = counts + N;
        int* bsum      = offsets + N + 1;
        int* edge_list = bsum + 64;
        uintptr_t p = (uintptr_t)(edge_list + E);
        p = (p + 15) & ~(uintptr_t)15;
        unsigned int* eb = (unsigned int*)p;
        unsigned int* aggb32 = eb + (size_t)E * 64;

        hipMemsetAsync(counts, 0, (size_t)N * sizeof(int), stream);

        long long nq = (long long)E * 32;   // float4 count of e
        conv_hist_kernel<<<2048, 256, 0, stream>>>(e, tgt, counts, eb, nq, E);

        int nb = (N + 1023) / 1024;   // 49
        scan1_kernel<<<nb, 1024, 0, stream>>>(counts, offsets, bsum, N);
        scan23_kernel<<<nb, 1024, 0, stream>>>(offsets, bsum, N, E, nb);
        fill_kernel<<<(E + 255) / 256, 256, 0, stream>>>(tgt, offsets, counts, edge_list, E);

        gather_eb_kernel<<<(N + 3) / 4, 256, 0, stream>>>(eb, edge_list, offsets, aggb32, N);

        int ngroups = (N + HF - 1) / HF;  // 391
        mlp_mfma_kernel<<<256, 512, 0, stream>>>((const unsigned short*)aggb32, v,
                                                 w1, b1, w2, b2, out, N, ngroups);
    } else {
        hipMemsetAsync(out, 0, (size_t)N * HF * sizeof(float), stream);
        long long total_t = (long long)E * 32;
        scatter_add_kernel<<<(int)((total_t + 255) / 256), 256, 0, stream>>>(e, tgt, out, E);
        mlp_kernel<<<512, 512, 0, stream>>>(out, v, w1, b1, w2, b2, N);
    }
}

// Round 10
// 200.387 us; speedup vs baseline: 6.3152x; 1.2048x over previous
//
#include <hip/hip_runtime.h>
#include <math.h>

#define HF 128
#define WPAD 136      // padded LDS row stride (bf16 elems): 272 B, 2-way banks only (free)

typedef short bfrag __attribute__((ext_vector_type(8)));   // 8 bf16 (4 VGPRs) - MFMA A/B frag
typedef float facc  __attribute__((ext_vector_type(4)));   // 4 f32 - MFMA C/D frag
typedef float f4v   __attribute__((ext_vector_type(4)));

__device__ __forceinline__ unsigned short f2bf(float x) {
    unsigned int u = __float_as_uint(x);
    unsigned int r = (u + 0x7FFFu + ((u >> 16) & 1u)) >> 16;
    return (unsigned short)r;
}

__device__ __forceinline__ float ssp(float x) {
    const float SHIFT = 0.69314718055994531f;
    return (x > 0.f) ? (x + log1pf(expf(-x)) - SHIFT)
                     : (log1pf(expf(x)) - SHIFT);
}

// ---------------------------------------------------------------------------
// CSR build: histogram -> scan -> fill
// ---------------------------------------------------------------------------
__global__ void hist_kernel(const int* __restrict__ tgt, int* __restrict__ counts, int E) {
    int eid = blockIdx.x * blockDim.x + threadIdx.x;
    if (eid < E) atomicAdd(&counts[tgt[eid]], 1);
}

__global__ __launch_bounds__(1024) void scan1_kernel(const int* __restrict__ counts,
                                                     int* __restrict__ offsets,
                                                     int* __restrict__ bsum, int N) {
    __shared__ int ws[16];
    int t = threadIdx.x;
    int i = blockIdx.x * 1024 + t;
    int lane = t & 63, wv = t >> 6;
    int val = (i < N) ? counts[i] : 0;
    int x = val;
    #pragma unroll
    for (int d = 1; d < 64; d <<= 1) {
        int y = __shfl_up(x, d, 64);
        if (lane >= d) x += y;
    }
    if (lane == 63) ws[wv] = x;
    __syncthreads();
    if (wv == 0) {
        int s = (lane < 16) ? ws[lane] : 0;
        #pragma unroll
        for (int d = 1; d < 16; d <<= 1) {
            int y = __shfl_up(s, d, 64);
            if (lane >= d) s += y;
        }
        if (lane < 16) ws[lane] = s;
    }
    __syncthreads();
    int pre = ((wv > 0) ? ws[wv - 1] : 0) + (x - val);
    if (i < N) offsets[i] = pre;
    if (t == 0) bsum[blockIdx.x] = ws[15];
}

__global__ __launch_bounds__(1024) void scan23_kernel(int* __restrict__ offsets,
                                                      const int* __restrict__ bsum,
                                                      int N, int E, int nb) {
    __shared__ int pre_s;
    int t = threadIdx.x;
    if (t < 64) {
        int v = (t < nb && t < (int)blockIdx.x) ? bsum[t] : 0;
        #pragma unroll
        for (int d = 32; d > 0; d >>= 1) v += __shfl_down(v, d, 64);
        if (t == 0) pre_s = v;
    }
    __syncthreads();
    int i = blockIdx.x * 1024 + t;
    if (i < N) offsets[i] += pre_s;
    if (blockIdx.x == 0 && t == 0) offsets[N] = E;
}

// counts doubles as cursor: atomicSub yields a unique slot in [0, count)
__global__ void fill_kernel(const int* __restrict__ tgt, const int* __restrict__ offsets,
                            int* __restrict__ counts, int* __restrict__ edge_list, int E) {
    int eid = blockIdx.x * blockDim.x + threadIdx.x;
    if (eid >= E) return;
    int t = tgt[eid];
    int pos = atomicSub(&counts[t], 1) - 1;
    edge_list[offsets[t] + pos] = eid;
}

// ---------------------------------------------------------------------------
// Gather-sum into bf16 agg: ONE NODE PER HALF-WAVE (32 lanes x float4 = one
// 512 B row). 4 rows in flight per half-wave (8/wave). Nontemporal row loads
// (read-once stream; keep L2 for edge_list/offsets).
// ---------------------------------------------------------------------------
__global__ __launch_bounds__(256) void gather_kernel(const float* __restrict__ e,
                                                     const int* __restrict__ edge_list,
                                                     const int* __restrict__ offsets,
                                                     unsigned short* __restrict__ aggb, int N) {
    int node = (blockIdx.x * blockDim.x + threadIdx.x) >> 5;   // half-wave id
    if (node >= N) return;
    int chunk = threadIdx.x & 31;     // float4 chunk within the 128-wide row
    int beg = offsets[node], end = offsets[node + 1];
    f4v a0 = {0.f, 0.f, 0.f, 0.f};
    f4v a1 = {0.f, 0.f, 0.f, 0.f};
    f4v a2 = {0.f, 0.f, 0.f, 0.f};
    f4v a3 = {0.f, 0.f, 0.f, 0.f};
    int j = beg;
    for (; j + 4 <= end; j += 4) {
        int e0 = edge_list[j + 0];
        int e1 = edge_list[j + 1];
        int e2 = edge_list[j + 2];
        int e3 = edge_list[j + 3];
        a0 += __builtin_nontemporal_load((const f4v*)(e + (size_t)e0 * HF) + chunk);
        a1 += __builtin_nontemporal_load((const f4v*)(e + (size_t)e1 * HF) + chunk);
        a2 += __builtin_nontemporal_load((const f4v*)(e + (size_t)e2 * HF) + chunk);
        a3 += __builtin_nontemporal_load((const f4v*)(e + (size_t)e3 * HF) + chunk);
    }
    if (j + 2 <= end) {
        int e0 = edge_list[j + 0];
        int e1 = edge_list[j + 1];
        a0 += __builtin_nontemporal_load((const f4v*)(e + (size_t)e0 * HF) + chunk);
        a1 += __builtin_nontemporal_load((const f4v*)(e + (size_t)e1 * HF) + chunk);
        j += 2;
    }
    if (j < end) {
        int e0 = edge_list[j];
        a2 += __builtin_nontemporal_load((const f4v*)(e + (size_t)e0 * HF) + chunk);
    }
    a0 += a1; a2 += a3; a0 += a2;
    ushort4 o;
    o.x = f2bf(a0.x); o.y = f2bf(a0.y); o.z = f2bf(a0.z); o.w = f2bf(a0.w);
    ((ushort4*)(aggb + (size_t)node * HF))[chunk] = o;
}

// ---------------------------------------------------------------------------
// MFMA MLP: out = v + ( ssp(agg @ w1 + b1) @ w2 + b2 )
// One 128-node tile per block, 391 blocks, 512 thr (8 waves).
// Single 34 KB wt buffer: w1^T for pass A, restaged to w2^T for pass B
// => LDS 68 KB => 2 blocks/CU.
// wave w: rows (w&3)*32, cols (w>>2)*64. 16x16x32 bf16 MFMA.
// C/D: col=lane&15, row=4*(lane>>4)+i  [guide m89].
// ---------------------------------------------------------------------------
__global__ __launch_bounds__(512) void mlp_mfma_kernel(
        const unsigned short* __restrict__ aggb,
        const float* __restrict__ v,
        const float* __restrict__ w1, const float* __restrict__ b1,
        const float* __restrict__ w2, const float* __restrict__ b2,
        float* __restrict__ out, int N) {
    __shared__ unsigned short wt[HF * WPAD];     // 34 KB: w1^T then w2^T
    __shared__ unsigned short atile[HF * WPAD];  // 34 KB: agg tile, then h tile

    int tid = threadIdx.x;
    int base = blockIdx.x * HF;

    // stage agg tile + w1^T
    for (int idx = tid; idx < HF * 16; idx += 512) {
        int r = idx >> 4, c = idx & 15;
        int row = base + r;
        bfrag val = {0,0,0,0,0,0,0,0};
        if (row < N) val = *(const bfrag*)(aggb + (size_t)row * HF + c * 8);
        *(bfrag*)(atile + r * WPAD + c * 8) = val;
    }
    for (int idx = tid; idx < HF * HF; idx += 512) {
        int k = idx >> 7, n = idx & 127;
        wt[n * WPAD + k] = f2bf(w1[idx]);
    }

    int w = tid >> 6, lane = tid & 63;
    int wr = (w & 3) * 32;       // row block base
    int wchalf = (w >> 2) * 64;  // col half base
    int lr = lane & 15;
    int kg = lane >> 4;          // k-group 0..3
    float bias1[4], bias2[4];
    #pragma unroll
    for (int nt = 0; nt < 4; ++nt) {
        int col = wchalf + nt * 16 + lr;
        bias1[nt] = b1[col];
        bias2[nt] = b2[col];
    }
    __syncthreads();

    // pass A: h = ssp(agg @ w1 + b1)
    facc acc[2][4];
    #pragma unroll
    for (int m = 0; m < 2; ++m)
        #pragma unroll
        for (int nt = 0; nt < 4; ++nt)
            acc[m][nt] = (facc){0.f, 0.f, 0.f, 0.f};
    #pragma unroll
    for (int ks = 0; ks < 4; ++ks) {
        int k0 = ks * 32 + kg * 8;
        bfrag a0 = *(const bfrag*)(atile + (wr + lr) * WPAD + k0);
        bfrag a1 = *(const bfrag*)(atile + (wr + 16 + lr) * WPAD + k0);
        #pragma unroll
        for (int nt = 0; nt < 4; ++nt) {
            bfrag b = *(const bfrag*)(wt + (wchalf + nt * 16 + lr) * WPAD + k0);
            acc[0][nt] = __builtin_amdgcn_mfma_f32_16x16x32_bf16(a0, b, acc[0][nt], 0, 0, 0);
            acc[1][nt] = __builtin_amdgcn_mfma_f32_16x16x32_bf16(a1, b, acc[1][nt], 0, 0, 0);
        }
    }
    __syncthreads();   // pass-A reads of atile + wt done

    // restage w2^T; write h into atile
    for (int idx = tid; idx < HF * HF; idx += 512) {
        int k = idx >> 7, n = idx & 127;
        wt[n * WPAD + k] = f2bf(w2[idx]);
    }
    #pragma unroll
    for (int m = 0; m < 2; ++m) {
        int rbase = wr + m * 16 + kg * 4;
        #pragma unroll
        for (int nt = 0; nt < 4; ++nt) {
            int col = wchalf + nt * 16 + lr;
            #pragma unroll
            for (int i = 0; i < 4; ++i) {
                float h = ssp(acc[m][nt][i] + bias1[nt]);
                atile[(rbase + i) * WPAD + col] = f2bf(h);
            }
        }
    }
    __syncthreads();

    // pass B: out = v + h @ w2 + b2
    facc acc2[2][4];
    #pragma unroll
    for (int m = 0; m < 2; ++m)
        #pragma unroll
        for (int nt = 0; nt < 4; ++nt)
            acc2[m][nt] = (facc){0.f, 0.f, 0.f, 0.f};
    #pragma unroll
    for (int ks = 0; ks < 4; ++ks) {
        int k0 = ks * 32 + kg * 8;
        bfrag a0 = *(const bfrag*)(atile + (wr + lr) * WPAD + k0);
        bfrag a1 = *(const bfrag*)(atile + (wr + 16 + lr) * WPAD + k0);
        #pragma unroll
        for (int nt = 0; nt < 4; ++nt) {
            bfrag b = *(const bfrag*)(wt + (wchalf + nt * 16 + lr) * WPAD + k0);
            acc2[0][nt] = __builtin_amdgcn_mfma_f32_16x16x32_bf16(a0, b, acc2[0][nt], 0, 0, 0);
            acc2[1][nt] = __builtin_amdgcn_mfma_f32_16x16x32_bf16(a1, b, acc2[1][nt], 0, 0, 0);
        }
    }

    #pragma unroll
    for (int m = 0; m < 2; ++m) {
        #pragma unroll
        for (int i = 0; i < 4; ++i) {
            int row = base + wr + m * 16 + kg * 4 + i;
            if (row < N) {
                #pragma unroll
                for (int nt = 0; nt < 4; ++nt) {
                    int col = wchalf + nt * 16 + lr;
                    out[(size_t)row * HF + col] = acc2[m][nt][i] + bias2[nt] + v[(size_t)row * HF + col];
                }
            }
        }
    }
}

// ---------------------------------------------------------------------------
// Fallback path (ws too small): atomic scatter + f32 vector MLP
// ---------------------------------------------------------------------------
__global__ void scatter_add_kernel(const float* __restrict__ e,
                                   const int* __restrict__ tgt,
                                   float* __restrict__ agg, int E) {
    int t = blockIdx.x * blockDim.x + threadIdx.x;
    int eid = t >> 5;
    if (eid >= E) return;
    int c = t & 31;
    int dst = tgt[eid];
    float4 val = *reinterpret_cast<const float4*>(e + (size_t)eid * HF + c * 4);
    float* p = agg + (size_t)dst * HF + c * 4;
    unsafeAtomicAdd(p + 0, val.x);
    unsafeAtomicAdd(p + 1, val.y);
    unsafeAtomicAdd(p + 2, val.z);
    unsafeAtomicAdd(p + 3, val.w);
}

__device__ __forceinline__ void fma4(float4& acc, float a, const float4& w) {
    acc.x = fmaf(a, w.x, acc.x);
    acc.y = fmaf(a, w.y, acc.y);
    acc.z = fmaf(a, w.z, acc.z);
    acc.w = fmaf(a, w.w, acc.w);
}

__global__ __launch_bounds__(512) void mlp_kernel(
        float* __restrict__ data, const float* __restrict__ v,
        const float* __restrict__ w1, const float* __restrict__ b1,
        const float* __restrict__ w2, const float* __restrict__ b2, int N) {
    __shared__ float w1s[HF * HF];
    __shared__ float w2s[HF * HF];
    __shared__ float tile[32][HF];
    int tid = threadIdx.x;
    float4* w1sv = (float4*)w1s; float4* w2sv = (float4*)w2s;
    for (int i = tid; i < HF * HF / 4; i += 512) {
        w1sv[i] = ((const float4*)w1)[i];
        w2sv[i] = ((const float4*)w2)[i];
    }
    int nl = tid >> 5, fblk = tid & 31;
    float4 bb1 = ((const float4*)b1)[fblk];
    float4 bb2 = ((const float4*)b2)[fblk];
    float4* tilev = (float4*)tile;
    int ngroups = (N + 31) / 32;
    for (int g = blockIdx.x; g < ngroups; g += gridDim.x) {
        int base = g * 32;
        __syncthreads();
        for (int i = tid; i < 32 * (HF / 4); i += 512) {
            int node = base + (i >> 5);
            float4 val = make_float4(0.f, 0.f, 0.f, 0.f);
            if (node < N) val = ((const float4*)data)[(size_t)node * (HF / 4) + (i & 31)];
            tilev[i] = val;
        }
        __syncthreads();
        float4 a0 = bb1, a1 = bb1;
        #pragma unroll 8
        for (int k = 0; k < HF; ++k) {
            float x0 = tile[nl][k], x1 = tile[nl + 16][k];
            float4 w = w1sv[k * 32 + fblk];
            fma4(a0, x0, w); fma4(a1, x1, w);
        }
        a0.x = ssp(a0.x); a0.y = ssp(a0.y); a0.z = ssp(a0.z); a0.w = ssp(a0.w);
        a1.x = ssp(a1.x); a1.y = ssp(a1.y); a1.z = ssp(a1.z); a1.w = ssp(a1.w);
        __syncthreads();
        tilev[nl * 32 + fblk] = a0;
        tilev[(nl + 16) * 32 + fblk] = a1;
        __syncthreads();
        float4 c0 = bb2, c1 = bb2;
        #pragma unroll 8
        for (int k = 0; k < HF; ++k) {
            float x0 = tile[nl][k], x1 = tile[nl + 16][k];
            float4 w = w2sv[k * 32 + fblk];
            fma4(c0, x0, w); fma4(c1, x1, w);
        }
        int n0 = base + nl, n1 = base + nl + 16;
        if (n0 < N) {
            float4 vv = ((const float4*)v)[(size_t)n0 * 32 + fblk];
            c0.x += vv.x; c0.y += vv.y; c0.z += vv.z; c0.w += vv.w;
            ((float4*)data)[(size_t)n0 * 32 + fblk] = c0;
        }
        if (n1 < N) {
            float4 vv = ((const float4*)v)[(size_t)n1 * 32 + fblk];
            c1.x += vv.x; c1.y += vv.y; c1.z += vv.z; c1.w += vv.w;
            ((float4*)data)[(size_t)n1 * 32 + fblk] = c1;
        }
    }
}

extern "C" void kernel_launch(void* const* d_in, const int* in_sizes, int n_in,
                              void* d_out, int out_size, void* d_ws, size_t ws_size,
                              hipStream_t stream) {
    const float* v  = (const float*)d_in[0];
    const float* e  = (const float*)d_in[1];
    const int*   ei = (const int*)d_in[2];
    const float* w1 = (const float*)d_in[3];
    const float* b1 = (const float*)d_in[4];
    const float* w2 = (const float*)d_in[5];
    const float* b2 = (const float*)d_in[6];
    float* out = (float*)d_out;

    int N = in_sizes[0] / HF;    // 50000
    int E = in_sizes[2] / 2;     // 600000
    const int* tgt = ei + E;     // edge_index[1]

    // ws layout: counts[N] | offsets[N+1] | bsum[64] | edge_list[E] | aggb[N*HF bf16]
    size_t ints = (size_t)N + (N + 1) + 64 + E;
    size_t needed = ints * 4 + 16 + (size_t)N * HF * 2;
    if (ws_size >= needed) {
        int* counts    = (int*)d_ws;
        int* offsets   = counts + N;
        int* bsum      = offsets + N + 1;
        int* edge_list = bsum + 64;
        uintptr_t p = (uintptr_t)(edge_list + E);
        p = (p + 15) & ~(uintptr_t)15;
        unsigned short* aggb = (unsigned short*)p;

        hipMemsetAsync(counts, 0, (size_t)N * sizeof(int), stream);

        int eb = (E + 255) / 256;
        int nb = (N + 1023) / 1024;   // 49
        hist_kernel<<<eb, 256, 0, stream>>>(tgt, counts, E);
        scan1_kernel<<<nb, 1024, 0, stream>>>(counts, offsets, bsum, N);
        scan23_kernel<<<nb, 1024, 0, stream>>>(offsets, bsum, N, E, nb);
        fill_kernel<<<eb, 256, 0, stream>>>(tgt, offsets, counts, edge_list, E);

        // one node per half-wave: 8 nodes per 256-thr block
        gather_kernel<<<(N + 7) / 8, 256, 0, stream>>>(e, edge_list, offsets, aggb, N);

        int ngroups = (N + HF - 1) / HF;  // 391
        mlp_mfma_kernel<<<ngroups, 512, 0, stream>>>(aggb, v, w1, b1, w2, b2, out, N);
    } else {
        hipMemsetAsync(out, 0, (size_t)N * HF * sizeof(float), stream);
        long long total_t = (long long)E * 32;
        scatter_add_kernel<<<(int)((total_t + 255) / 256), 256, 0, stream>>>(e, tgt, out, E);
        mlp_kernel<<<512, 512, 0, stream>>>(out, v, w1, b1, w2, b2, N);
    }
}

// Round 11
// 199.288 us; speedup vs baseline: 6.3500x; 1.0055x over previous
//
#include <hip/hip_runtime.h>
#include <math.h>

#define HF 128
#define WPAD 136      // padded LDS row stride (bf16 elems): 272 B, 2-way banks only (free)

typedef short bfrag __attribute__((ext_vector_type(8)));   // 8 bf16 (4 VGPRs) - MFMA A/B frag
typedef float facc  __attribute__((ext_vector_type(4)));   // 4 f32 - MFMA C/D frag
typedef float f4v   __attribute__((ext_vector_type(4)));

__device__ __forceinline__ unsigned short f2bf(float x) {
    unsigned int u = __float_as_uint(x);
    unsigned int r = (u + 0x7FFFu + ((u >> 16) & 1u)) >> 16;
    return (unsigned short)r;
}

__device__ __forceinline__ float ssp(float x) {
    const float SHIFT = 0.69314718055994531f;
    return (x > 0.f) ? (x + log1pf(expf(-x)) - SHIFT)
                     : (log1pf(expf(x)) - SHIFT);
}

// ---------------------------------------------------------------------------
// CSR build: histogram -> block-local scan -> 1-wave block-prefix -> fill
// (fill/gather add bpre[i>>10] on the fly; no full-N fixup pass)
// ---------------------------------------------------------------------------
__global__ void hist_kernel(const int* __restrict__ tgt, int* __restrict__ counts, int E) {
    int eid = blockIdx.x * blockDim.x + threadIdx.x;
    if (eid < E) atomicAdd(&counts[tgt[eid]], 1);
}

// block-local exclusive scan; bsum[b] = block total
__global__ __launch_bounds__(1024) void scan1_kernel(const int* __restrict__ counts,
                                                     int* __restrict__ offsets,
                                                     int* __restrict__ bsum, int N) {
    __shared__ int ws[16];
    int t = threadIdx.x;
    int i = blockIdx.x * 1024 + t;
    int lane = t & 63, wv = t >> 6;
    int val = (i < N) ? counts[i] : 0;
    int x = val;
    #pragma unroll
    for (int d = 1; d < 64; d <<= 1) {
        int y = __shfl_up(x, d, 64);
        if (lane >= d) x += y;
    }
    if (lane == 63) ws[wv] = x;
    __syncthreads();
    if (wv == 0) {
        int s = (lane < 16) ? ws[lane] : 0;
        #pragma unroll
        for (int d = 1; d < 16; d <<= 1) {
            int y = __shfl_up(s, d, 64);
            if (lane >= d) s += y;
        }
        if (lane < 16) ws[lane] = s;
    }
    __syncthreads();
    int pre = ((wv > 0) ? ws[wv - 1] : 0) + (x - val);
    if (i < N) offsets[i] = pre;          // block-local exclusive prefix
    if (t == 0) bsum[blockIdx.x] = ws[15];
}

// exclusive scan of block sums (nb <= 64), one wave
__global__ void scan2_kernel(const int* __restrict__ bsum, int* __restrict__ bpre, int nb) {
    int lane = threadIdx.x & 63;
    int v = (lane < nb) ? bsum[lane] : 0;
    int x = v;
    #pragma unroll
    for (int d = 1; d < 64; d <<= 1) {
        int y = __shfl_up(x, d, 64);
        if (lane >= d) x += y;
    }
    if (lane < nb) bpre[lane] = x - v;
}

// counts doubles as cursor: atomicSub yields a unique slot in [0, count)
__global__ void fill_kernel(const int* __restrict__ tgt, const int* __restrict__ offsets,
                            const int* __restrict__ bpre, int* __restrict__ counts,
                            int* __restrict__ edge_list, int E) {
    int eid = blockIdx.x * blockDim.x + threadIdx.x;
    if (eid >= E) return;
    int t = tgt[eid];
    int pos = atomicSub(&counts[t], 1) - 1;
    edge_list[offsets[t] + bpre[t >> 10] + pos] = eid;
}

// ---------------------------------------------------------------------------
// Gather-sum into bf16 agg: ONE NODE PER HALF-WAVE (32 lanes x float4 = one
// 512 B row). 4 rows in flight per half-wave. Nontemporal row loads.
// Global offset = offsets[i] + bpre[i>>10]; end for last node = E.
// ---------------------------------------------------------------------------
__global__ __launch_bounds__(256) void gather_kernel(const float* __restrict__ e,
                                                     const int* __restrict__ edge_list,
                                                     const int* __restrict__ offsets,
                                                     const int* __restrict__ bpre,
                                                     unsigned short* __restrict__ aggb,
                                                     int N, int E) {
    int node = (blockIdx.x * blockDim.x + threadIdx.x) >> 5;   // half-wave id
    if (node >= N) return;
    int chunk = threadIdx.x & 31;     // float4 chunk within the 128-wide row
    int beg = offsets[node] + bpre[node >> 10];
    int np1 = node + 1;
    int end = (np1 < N) ? (offsets[np1] + bpre[np1 >> 10]) : E;
    f4v a0 = {0.f, 0.f, 0.f, 0.f};
    f4v a1 = {0.f, 0.f, 0.f, 0.f};
    f4v a2 = {0.f, 0.f, 0.f, 0.f};
    f4v a3 = {0.f, 0.f, 0.f, 0.f};
    int j = beg;
    for (; j + 4 <= end; j += 4) {
        int e0 = edge_list[j + 0];
        int e1 = edge_list[j + 1];
        int e2 = edge_list[j + 2];
        int e3 = edge_list[j + 3];
        a0 += __builtin_nontemporal_load((const f4v*)(e + (size_t)e0 * HF) + chunk);
        a1 += __builtin_nontemporal_load((const f4v*)(e + (size_t)e1 * HF) + chunk);
        a2 += __builtin_nontemporal_load((const f4v*)(e + (size_t)e2 * HF) + chunk);
        a3 += __builtin_nontemporal_load((const f4v*)(e + (size_t)e3 * HF) + chunk);
    }
    if (j + 2 <= end) {
        int e0 = edge_list[j + 0];
        int e1 = edge_list[j + 1];
        a0 += __builtin_nontemporal_load((const f4v*)(e + (size_t)e0 * HF) + chunk);
        a1 += __builtin_nontemporal_load((const f4v*)(e + (size_t)e1 * HF) + chunk);
        j += 2;
    }
    if (j < end) {
        int e0 = edge_list[j];
        a2 += __builtin_nontemporal_load((const f4v*)(e + (size_t)e0 * HF) + chunk);
    }
    a0 += a1; a2 += a3; a0 += a2;
    ushort4 o;
    o.x = f2bf(a0.x); o.y = f2bf(a0.y); o.z = f2bf(a0.z); o.w = f2bf(a0.w);
    ((ushort4*)(aggb + (size_t)node * HF))[chunk] = o;
}

// ---------------------------------------------------------------------------
// MFMA MLP: out = v + ( ssp(agg @ w1 + b1) @ w2 + b2 )
// One 128-node tile per block, 391 blocks, 512 thr (8 waves).
// Single 34 KB wt buffer: w1^T for pass A, restaged to w2^T for pass B
// => LDS 68 KB => 2 blocks/CU.
// wave w: rows (w&3)*32, cols (w>>2)*64. 16x16x32 bf16 MFMA.
// C/D: col=lane&15, row=4*(lane>>4)+i  [guide m89].
// ---------------------------------------------------------------------------
__global__ __launch_bounds__(512) void mlp_mfma_kernel(
        const unsigned short* __restrict__ aggb,
        const float* __restrict__ v,
        const float* __restrict__ w1, const float* __restrict__ b1,
        const float* __restrict__ w2, const float* __restrict__ b2,
        float* __restrict__ out, int N) {
    __shared__ unsigned short wt[HF * WPAD];     // 34 KB: w1^T then w2^T
    __shared__ unsigned short atile[HF * WPAD];  // 34 KB: agg tile, then h tile

    int tid = threadIdx.x;
    int base = blockIdx.x * HF;

    // stage agg tile + w1^T
    for (int idx = tid; idx < HF * 16; idx += 512) {
        int r = idx >> 4, c = idx & 15;
        int row = base + r;
        bfrag val = {0,0,0,0,0,0,0,0};
        if (row < N) val = *(const bfrag*)(aggb + (size_t)row * HF + c * 8);
        *(bfrag*)(atile + r * WPAD + c * 8) = val;
    }
    for (int idx = tid; idx < HF * HF; idx += 512) {
        int k = idx >> 7, n = idx & 127;
        wt[n * WPAD + k] = f2bf(w1[idx]);
    }

    int w = tid >> 6, lane = tid & 63;
    int wr = (w & 3) * 32;       // row block base
    int wchalf = (w >> 2) * 64;  // col half base
    int lr = lane & 15;
    int kg = lane >> 4;          // k-group 0..3
    float bias1[4], bias2[4];
    #pragma unroll
    for (int nt = 0; nt < 4; ++nt) {
        int col = wchalf + nt * 16 + lr;
        bias1[nt] = b1[col];
        bias2[nt] = b2[col];
    }
    __syncthreads();

    // pass A: h = ssp(agg @ w1 + b1)
    facc acc[2][4];
    #pragma unroll
    for (int m = 0; m < 2; ++m)
        #pragma unroll
        for (int nt = 0; nt < 4; ++nt)
            acc[m][nt] = (facc){0.f, 0.f, 0.f, 0.f};
    #pragma unroll
    for (int ks = 0; ks < 4; ++ks) {
        int k0 = ks * 32 + kg * 8;
        bfrag a0 = *(const bfrag*)(atile + (wr + lr) * WPAD + k0);
        bfrag a1 = *(const bfrag*)(atile + (wr + 16 + lr) * WPAD + k0);
        #pragma unroll
        for (int nt = 0; nt < 4; ++nt) {
            bfrag b = *(const bfrag*)(wt + (wchalf + nt * 16 + lr) * WPAD + k0);
            acc[0][nt] = __builtin_amdgcn_mfma_f32_16x16x32_bf16(a0, b, acc[0][nt], 0, 0, 0);
            acc[1][nt] = __builtin_amdgcn_mfma_f32_16x16x32_bf16(a1, b, acc[1][nt], 0, 0, 0);
        }
    }
    __syncthreads();   // pass-A reads of atile + wt done

    // restage w2^T; write h into atile
    for (int idx = tid; idx < HF * HF; idx += 512) {
        int k = idx >> 7, n = idx & 127;
        wt[n * WPAD + k] = f2bf(w2[idx]);
    }
    #pragma unroll
    for (int m = 0; m < 2; ++m) {
        int rbase = wr + m * 16 + kg * 4;
        #pragma unroll
        for (int nt = 0; nt < 4; ++nt) {
            int col = wchalf + nt * 16 + lr;
            #pragma unroll
            for (int i = 0; i < 4; ++i) {
                float h = ssp(acc[m][nt][i] + bias1[nt]);
                atile[(rbase + i) * WPAD + col] = f2bf(h);
            }
        }
    }
    __syncthreads();

    // pass B: out = v + h @ w2 + b2
    facc acc2[2][4];
    #pragma unroll
    for (int m = 0; m < 2; ++m)
        #pragma unroll
        for (int nt = 0; nt < 4; ++nt)
            acc2[m][nt] = (facc){0.f, 0.f, 0.f, 0.f};
    #pragma unroll
    for (int ks = 0; ks < 4; ++ks) {
        int k0 = ks * 32 + kg * 8;
        bfrag a0 = *(const bfrag*)(atile + (wr + lr) * WPAD + k0);
        bfrag a1 = *(const bfrag*)(atile + (wr + 16 + lr) * WPAD + k0);
        #pragma unroll
        for (int nt = 0; nt < 4; ++nt) {
            bfrag b = *(const bfrag*)(wt + (wchalf + nt * 16 + lr) * WPAD + k0);
            acc2[0][nt] = __builtin_amdgcn_mfma_f32_16x16x32_bf16(a0, b, acc2[0][nt], 0, 0, 0);
            acc2[1][nt] = __builtin_amdgcn_mfma_f32_16x16x32_bf16(a1, b, acc2[1][nt], 0, 0, 0);
        }
    }

    #pragma unroll
    for (int m = 0; m < 2; ++m) {
        #pragma unroll
        for (int i = 0; i < 4; ++i) {
            int row = base + wr + m * 16 + kg * 4 + i;
            if (row < N) {
                #pragma unroll
                for (int nt = 0; nt < 4; ++nt) {
                    int col = wchalf + nt * 16 + lr;
                    out[(size_t)row * HF + col] = acc2[m][nt][i] + bias2[nt] + v[(size_t)row * HF + col];
                }
            }
        }
    }
}

// ---------------------------------------------------------------------------
// Fallback path (ws too small): atomic scatter + f32 vector MLP
// ---------------------------------------------------------------------------
__global__ void scatter_add_kernel(const float* __restrict__ e,
                                   const int* __restrict__ tgt,
                                   float* __restrict__ agg, int E) {
    int t = blockIdx.x * blockDim.x + threadIdx.x;
    int eid = t >> 5;
    if (eid >= E) return;
    int c = t & 31;
    int dst = tgt[eid];
    float4 val = *reinterpret_cast<const float4*>(e + (size_t)eid * HF + c * 4);
    float* p = agg + (size_t)dst * HF + c * 4;
    unsafeAtomicAdd(p + 0, val.x);
    unsafeAtomicAdd(p + 1, val.y);
    unsafeAtomicAdd(p + 2, val.z);
    unsafeAtomicAdd(p + 3, val.w);
}

__device__ __forceinline__ void fma4(float4& acc, float a, const float4& w) {
    acc.x = fmaf(a, w.x, acc.x);
    acc.y = fmaf(a, w.y, acc.y);
    acc.z = fmaf(a, w.z, acc.z);
    acc.w = fmaf(a, w.w, acc.w);
}

__global__ __launch_bounds__(512) void mlp_kernel(
        float* __restrict__ data, const float* __restrict__ v,
        const float* __restrict__ w1, const float* __restrict__ b1,
        const float* __restrict__ w2, const float* __restrict__ b2, int N) {
    __shared__ float w1s[HF * HF];
    __shared__ float w2s[HF * HF];
    __shared__ float tile[32][HF];
    int tid = threadIdx.x;
    float4* w1sv = (float4*)w1s; float4* w2sv = (float4*)w2s;
    for (int i = tid; i < HF * HF / 4; i += 512) {
        w1sv[i] = ((const float4*)w1)[i];
        w2sv[i] = ((const float4*)w2)[i];
    }
    int nl = tid >> 5, fblk = tid & 31;
    float4 bb1 = ((const float4*)b1)[fblk];
    float4 bb2 = ((const float4*)b2)[fblk];
    float4* tilev = (float4*)tile;
    int ngroups = (N + 31) / 32;
    for (int g = blockIdx.x; g < ngroups; g += gridDim.x) {
        int base = g * 32;
        __syncthreads();
        for (int i = tid; i < 32 * (HF / 4); i += 512) {
            int node = base + (i >> 5);
            float4 val = make_float4(0.f, 0.f, 0.f, 0.f);
            if (node < N) val = ((const float4*)data)[(size_t)node * (HF / 4) + (i & 31)];
            tilev[i] = val;
        }
        __syncthreads();
        float4 a0 = bb1, a1 = bb1;
        #pragma unroll 8
        for (int k = 0; k < HF; ++k) {
            float x0 = tile[nl][k], x1 = tile[nl + 16][k];
            float4 w = w1sv[k * 32 + fblk];
            fma4(a0, x0, w); fma4(a1, x1, w);
        }
        a0.x = ssp(a0.x); a0.y = ssp(a0.y); a0.z = ssp(a0.z); a0.w = ssp(a0.w);
        a1.x = ssp(a1.x); a1.y = ssp(a1.y); a1.z = ssp(a1.z); a1.w = ssp(a1.w);
        __syncthreads();
        tilev[nl * 32 + fblk] = a0;
        tilev[(nl + 16) * 32 + fblk] = a1;
        __syncthreads();
        float4 c0 = bb2, c1 = bb2;
        #pragma unroll 8
        for (int k = 0; k < HF; ++k) {
            float x0 = tile[nl][k], x1 = tile[nl + 16][k];
            float4 w = w2sv[k * 32 + fblk];
            fma4(c0, x0, w); fma4(c1, x1, w);
        }
        int n0 = base + nl, n1 = base + nl + 16;
        if (n0 < N) {
            float4 vv = ((const float4*)v)[(size_t)n0 * 32 + fblk];
            c0.x += vv.x; c0.y += vv.y; c0.z += vv.z; c0.w += vv.w;
            ((float4*)data)[(size_t)n0 * 32 + fblk] = c0;
        }
        if (n1 < N) {
            float4 vv = ((const float4*)v)[(size_t)n1 * 32 + fblk];
            c1.x += vv.x; c1.y += vv.y; c1.z += vv.z; c1.w += vv.w;
            ((float4*)data)[(size_t)n1 * 32 + fblk] = c1;
        }
    }
}

extern "C" void kernel_launch(void* const* d_in, const int* in_sizes, int n_in,
                              void* d_out, int out_size, void* d_ws, size_t ws_size,
                              hipStream_t stream) {
    const float* v  = (const float*)d_in[0];
    const float* e  = (const float*)d_in[1];
    const int*   ei = (const int*)d_in[2];
    const float* w1 = (const float*)d_in[3];
    const float* b1 = (const float*)d_in[4];
    const float* w2 = (const float*)d_in[5];
    const float* b2 = (const float*)d_in[6];
    float* out = (float*)d_out;

    int N = in_sizes[0] / HF;    // 50000
    int E = in_sizes[2] / 2;     // 600000
    const int* tgt = ei + E;     // edge_index[1]

    // ws layout: counts[N] | offsets[N+1] | bsum[64] | bpre[64] | edge_list[E] | aggb[N*HF bf16]
    size_t ints = (size_t)N + (N + 1) + 64 + 64 + E;
    size_t needed = ints * 4 + 16 + (size_t)N * HF * 2;
    if (ws_size >= needed) {
        int* counts    = (int*)d_ws;
        int* offsets   = counts + N;
        int* bsum      = offsets + N + 1;
        int* bpre      = bsum + 64;
        int* edge_list = bpre + 64;
        uintptr_t p = (uintptr_t)(edge_list + E);
        p = (p + 15) & ~(uintptr_t)15;
        unsigned short* aggb = (unsigned short*)p;

        hipMemsetAsync(counts, 0, (size_t)N * sizeof(int), stream);

        int eb = (E + 255) / 256;
        int nb = (N + 1023) / 1024;   // 49
        hist_kernel<<<eb, 256, 0, stream>>>(tgt, counts, E);
        scan1_kernel<<<nb, 1024, 0, stream>>>(counts, offsets, bsum, N);
        scan2_kernel<<<1, 64, 0, stream>>>(bsum, bpre, nb);
        fill_kernel<<<eb, 256, 0, stream>>>(tgt, offsets, bpre, counts, edge_list, E);

        // one node per half-wave: 8 nodes per 256-thr block
        gather_kernel<<<(N + 7) / 8, 256, 0, stream>>>(e, edge_list, offsets, bpre, aggb, N, E);

        int ngroups = (N + HF - 1) / HF;  // 391
        mlp_mfma_kernel<<<ngroups, 512, 0, stream>>>(aggb, v, w1, b1, w2, b2, out, N);
    } else {
        hipMemsetAsync(out, 0, (size_t)N * HF * sizeof(float), stream);
        long long total_t = (long long)E * 32;
        scatter_add_kernel<<<(int)((total_t + 255) / 256), 256, 0, stream>>>(e, tgt, out, E);
        mlp_kernel<<<512, 512, 0, stream>>>(out, v, w1, b1, w2, b2, N);
    }
}